// Round 11
// baseline (141.065 us; speedup 1.0000x reference)
//
#include <hip/hip_runtime.h>

typedef short bf16x8 __attribute__((ext_vector_type(8)));
typedef short bf16x4 __attribute__((ext_vector_type(4)));
typedef float floatx4 __attribute__((ext_vector_type(4)));

// fp32 -> bf16 round-to-nearest-even (finite inputs)
static __device__ __forceinline__ unsigned short f2bf(float f) {
  unsigned int x = __float_as_uint(f);
  x += 0x7fffu + ((x >> 16) & 1u);
  return (unsigned short)(x >> 16);
}

// KP (emb only, 64 blocks): emb -> eb bf16 + hn[k] = 0.5*||e_k||^2 ; block 0 zeroes loss.
__global__ __launch_bounds__(256) void k_prep(const float* __restrict__ emb,
                                              unsigned short* __restrict__ eb,
                                              float* __restrict__ hn,
                                              float* __restrict__ loss) {
  const int t = threadIdx.x, bid = blockIdx.x;
  if (bid == 0 && t == 0) *loss = 0.f;       // k_fullk (later dispatch) is the only reader/adder
  const int w = t >> 6, lane = t & 63;
  const int kb = (bid << 4) + (w << 2);
  for (int jj = 0; jj < 4; ++jj) {
    const int k = kb + jj;
    const float* er = emb + (k << 8);
    unsigned short* eo = eb + (k << 8);
    float ss = 0.f;
    for (int j = 0; j < 4; ++j) {
      const float v = er[j * 64 + lane];
      ss += v * v;
      eo[j * 64 + lane] = f2bf(v);
    }
    for (int off = 32; off >= 1; off >>= 1) ss += __shfl_xor(ss, off, 64);
    if (lane == 0) hn[k] = 0.5f * ss;
  }
}

// KB10 (E direct-to-register): 512 blocks x 256 thr x 64 rows, FULL 1024 codes/block.
// R9 post-mortem: timed k_fullk ~66us with NOTHING busy (Mfma 9%, VALU 12%, HBM 10%) --
// pure latency-bound at 2 waves/SIMD. Structural find: the es staging path was WAVE-PRIVATE
// reg->LDS->reg (wave w staged exactly the rows wave w reads) -- the whole es double-buffer
// + its lgkmcnt chain was overhead. THIS VERSION: each lane loads ITS OWN MFMA B-fragment
// straight from eb (L2-resident 512KB) into a 2-tile register double buffer (e0/e1, static
// indices only -- runtime-indexed ext_vector arrays spill to scratch). Tile kt's loads fly
// under tile kt-1's 32 MFMAs + compares. R1's version of this failed at depth-0 (no
// prefetch, 56us); the reg-dbuf is the fix. LDS now used only by phase-0 transpose + tail.
// Values/order bit-identical to R9: same eb bytes, same MFMA accumulation, same compares.
// (R10 was an infra failure -- container died twice; identical resubmission, audit clean:
//  eb max index 262,136 < 262,144 shorts; LDS/barrier structure unchanged from passing R8.)
__global__ __launch_bounds__(256, 2) void k_fullk(const float* __restrict__ x,
                                                  const unsigned short* __restrict__ eb,
                                                  const float* __restrict__ hn,
                                                  const float* __restrict__ emb,
                                                  float* __restrict__ out,
                                                  float* __restrict__ loss) {
  // LDS map (bytes) -- es regions only live in phase-0 (tile2/tmp) and tail (sel):
  //   [0, 33792)        tile2[64*264] shorts ; sel f32 overlays at tail
  //   [33792, 67584)    tmp[256*64] shorts (32768 B)
  //   [67584, 71680)    xred2[4][256] f32 (prologue) == hn_l[1024] f32 (main loop)
  //   [71680, 72704)    bvs[4][64] f32
  //   [72704, 73728)    bis[4][64] i32
  //   [73728, 73984)    idx_l[64] i32
  //   [73984, 74240)    xn2_l[64] f32
  __shared__ __align__(16) char smem[74240];
  unsigned short* tile2 = (unsigned short*)smem;
  unsigned short* tmp   = (unsigned short*)(smem + 33792);
  float* sel   = (float*)smem;
  float* hn_l  = (float*)(smem + 67584);
  float* xred2 = (float*)(smem + 67584);
  float* bvs   = (float*)(smem + 71680);
  int*   bis   = (int*)(smem + 72704);
  int*   idx_l = (int*)(smem + 73728);
  float* xn2_l = (float*)(smem + 73984);

  const int t = threadIdx.x;
  const int cq = t >> 6, lane = t & 63;        // wave = code-quarter
  const int r16 = lane & 15, quad = lane >> 4;
  const int n0 = blockIdx.x << 6;              // 64 rows/block
  const int b = n0 >> 10, hw0 = n0 & 1023;

  // per-lane B-frag base: code = cq*256 + kt*16 + r16, k-off = quad*8 + ci*32 (shorts)
  // tile kt offset = kt<<12 shorts.
  const unsigned short* ebl = eb + ((size_t)((cq << 8) + r16) << 8) + (quad << 3);

  // ---- issue E-tile0 direct-B loads EARLY (latency hides under the x read) ----
  bf16x8 e0[8], e1[8];
#pragma unroll
  for (int ci = 0; ci < 8; ++ci) e0[ci] = *(const bf16x8*)(ebl + (ci << 5));

  // ---- stage A: x float4 loads -> tmp[c][hw] (bf16), per-thread row-split ss (R8 form) ----
  {
    const int hwq = t & 15, cidx = t >> 4;
    const float* xpb = x + ((size_t)b << 18) + hw0 + (hwq << 2);
    float ss0 = 0.f, ss1 = 0.f, ss2 = 0.f, ss3 = 0.f;
    for (int p = 0; p < 16; ++p) {
      const int c = (p << 4) + cidx;
      const float4 v = *(const float4*)(xpb + ((size_t)c << 10));
      ss0 += v.x * v.x; ss1 += v.y * v.y; ss2 += v.z * v.z; ss3 += v.w * v.w;
      bf16x4 u;
      u[0] = (short)f2bf(v.x); u[1] = (short)f2bf(v.y);
      u[2] = (short)f2bf(v.z); u[3] = (short)f2bf(v.w);
      *(bf16x4*)(&tmp[(c << 6) + (hwq << 2)]) = u;                  // tmp[c*64 + hw]
    }
    xred2[t] = ss0; xred2[256 + t] = ss1; xred2[512 + t] = ss2; xred2[768 + t] = ss3;
  }
  __syncthreads();                             // tmp + xred2 complete

  // ---- stage B: tmp[c][hw] -> tile2[hw][c] (b16 reads 2-lanes/dword: conflict-free) ----
  {
    const int row = t & 63, wv = t >> 6;
    for (int s = 0; s < 8; ++s) {
      const int c8 = wv + (s << 2);
      bf16x8 u;
#pragma unroll
      for (int k = 0; k < 8; ++k) u[k] = (short)tmp[(((c8 << 3) + k) << 6) + row];
      *(bf16x8*)(&tile2[row * 264 + (c8 << 3)]) = u;
    }
  }
  // xn2 reduce (wave 0; hn_l overlay of xred2 happens after the barrier below)
  if (t < 64) {
    float s = 0.f;
    for (int ci2 = 0; ci2 < 16; ++ci2)
      s += xred2[(t & 3) * 256 + (ci2 << 4) + (t >> 2)];
    xn2_l[t] = s;
  }
  __syncthreads();                             // tile2 complete; xred2 consumed

  // A fragments from tile2: rows rg*16 + r16, c = quad*8 + ci*32 (bit-identical to R9)
  bf16x8 a[4][8];
  for (int rg = 0; rg < 4; ++rg) {
    const unsigned short* tr = tile2 + ((rg << 4) + r16) * 264 + (quad << 3);
#pragma unroll
    for (int ci = 0; ci < 8; ++ci) a[rg][ci] = *(const bf16x8*)(tr + (ci << 5));
  }
  // hn quarter fill: wave cq writes AND reads only its own quarter -> no barrier needed.
  for (int i = 0; i < 4; ++i)
    hn_l[(cq << 8) + (i << 6) + lane] = hn[(cq << 8) + (i << 6) + lane];

  // issue E-tile1 loads (fly under the first MFMA tiles)
#pragma unroll
  for (int ci = 0; ci < 8; ++ci) e1[ci] = *(const bf16x8*)(ebl + (1 << 12) + (ci << 5));

  float bv[4][4]; int bi[4][4];
  for (int rg = 0; rg < 4; ++rg)
    for (int r = 0; r < 4; ++r) { bv[rg][r] = -3.4e38f; bi[rg][r] = 0; }

  // ---- main loop: NO LDS, E from registers, 2-tile reg double-buffer ----
  // (2x unrolled so e0/e1 indices stay compile-time-static)
  for (int kt = 0; kt < 16; kt += 2) {
    {
      floatx4 acc0 = {0.f,0.f,0.f,0.f}, acc1 = {0.f,0.f,0.f,0.f};
      floatx4 acc2 = {0.f,0.f,0.f,0.f}, acc3 = {0.f,0.f,0.f,0.f};
      __builtin_amdgcn_s_setprio(1);
#pragma unroll
      for (int ci = 0; ci < 8; ++ci) {
        acc0 = __builtin_amdgcn_mfma_f32_16x16x32_bf16(a[0][ci], e0[ci], acc0, 0, 0, 0);
        acc1 = __builtin_amdgcn_mfma_f32_16x16x32_bf16(a[1][ci], e0[ci], acc1, 0, 0, 0);
        acc2 = __builtin_amdgcn_mfma_f32_16x16x32_bf16(a[2][ci], e0[ci], acc2, 0, 0, 0);
        acc3 = __builtin_amdgcn_mfma_f32_16x16x32_bf16(a[3][ci], e0[ci], acc3, 0, 0, 0);
      }
      __builtin_amdgcn_s_setprio(0);
      if (kt + 2 < 16) {                       // refill e0 <- tile kt+2 (flies under body B)
#pragma unroll
        for (int ci = 0; ci < 8; ++ci)
          e0[ci] = *(const bf16x8*)(ebl + ((kt + 2) << 12) + (ci << 5));
      }
      const int kglob = (cq << 8) + (kt << 4) + r16;
      const float h = hn_l[kglob];
#pragma unroll
      for (int r = 0; r < 4; ++r) {            // D: row = quad*4 + r, col(code) = r16
        float v;
        v = acc0[r] - h; if (v > bv[0][r]) { bv[0][r] = v; bi[0][r] = kglob; }
        v = acc1[r] - h; if (v > bv[1][r]) { bv[1][r] = v; bi[1][r] = kglob; }
        v = acc2[r] - h; if (v > bv[2][r]) { bv[2][r] = v; bi[2][r] = kglob; }
        v = acc3[r] - h; if (v > bv[3][r]) { bv[3][r] = v; bi[3][r] = kglob; }
      }
    }
    {
      floatx4 acc0 = {0.f,0.f,0.f,0.f}, acc1 = {0.f,0.f,0.f,0.f};
      floatx4 acc2 = {0.f,0.f,0.f,0.f}, acc3 = {0.f,0.f,0.f,0.f};
      __builtin_amdgcn_s_setprio(1);
#pragma unroll
      for (int ci = 0; ci < 8; ++ci) {
        acc0 = __builtin_amdgcn_mfma_f32_16x16x32_bf16(a[0][ci], e1[ci], acc0, 0, 0, 0);
        acc1 = __builtin_amdgcn_mfma_f32_16x16x32_bf16(a[1][ci], e1[ci], acc1, 0, 0, 0);
        acc2 = __builtin_amdgcn_mfma_f32_16x16x32_bf16(a[2][ci], e1[ci], acc2, 0, 0, 0);
        acc3 = __builtin_amdgcn_mfma_f32_16x16x32_bf16(a[3][ci], e1[ci], acc3, 0, 0, 0);
      }
      __builtin_amdgcn_s_setprio(0);
      if (kt + 3 < 16) {                       // refill e1 <- tile kt+3 (flies under body A')
#pragma unroll
        for (int ci = 0; ci < 8; ++ci)
          e1[ci] = *(const bf16x8*)(ebl + ((kt + 3) << 12) + (ci << 5));
      }
      const int kglob = (cq << 8) + ((kt + 1) << 4) + r16;
      const float h = hn_l[kglob];
#pragma unroll
      for (int r = 0; r < 4; ++r) {
        float v;
        v = acc0[r] - h; if (v > bv[0][r]) { bv[0][r] = v; bi[0][r] = kglob; }
        v = acc1[r] - h; if (v > bv[1][r]) { bv[1][r] = v; bi[1][r] = kglob; }
        v = acc2[r] - h; if (v > bv[2][r]) { bv[2][r] = v; bi[2][r] = kglob; }
        v = acc3[r] - h; if (v > bv[3][r]) { bv[3][r] = v; bi[3][r] = kglob; }
      }
    }
  }

  // reduce across the 16 code-columns (within each 16-lane group); ties -> lowest index
  for (int off = 8; off >= 1; off >>= 1)
    for (int rg = 0; rg < 4; ++rg)
      for (int r = 0; r < 4; ++r) {
        const float ov = __shfl_xor(bv[rg][r], off, 64);
        const int   oi = __shfl_xor(bi[rg][r], off, 64);
        if (ov > bv[rg][r] || (ov == bv[rg][r] && oi < bi[rg][r])) { bv[rg][r] = ov; bi[rg][r] = oi; }
      }
  if (r16 == 0) {
    for (int rg = 0; rg < 4; ++rg)
      for (int r = 0; r < 4; ++r) {
        const int row = (rg << 4) + (quad << 2) + r;
        bvs[(cq << 6) + row] = bv[rg][r];
        bis[(cq << 6) + row] = bi[rg][r];
      }
  }
  __syncthreads();                             // all quarters' bvs/bis visible

  // merge the 4 code-quarters (ascending q: strict > keeps lowest code on ties) + loss
  if (t < 64) {
    float vm = bvs[t]; int im = bis[t];
    for (int q = 1; q < 4; ++q) {
      const float v = bvs[(q << 6) + t];
      if (v > vm) { vm = v; im = bis[(q << 6) + t]; }
    }
    idx_l[t] = im;
    float lv = xn2_l[t] - 2.f * vm;            // = ||x_n - e_{im}||^2
    for (int off = 32; off >= 1; off >>= 1) lv += __shfl_xor(lv, off, 64);
    if (t == 0) atomicAdd(loss, lv * (1.25f / 8388608.0f));
  }
  __syncthreads();                             // idx_l ready; sel may overwrite tile2 region

  // gather winning code rows into LDS (coalesced 256B loads from L2-resident emb)
  for (int i = 0; i < 16; ++i) {
    const int row = (cq << 4) + i;
    const float* er = emb + ((size_t)idx_l[row] << 8);
    for (int j = 0; j < 4; ++j)
      sel[row * 257 + (j << 6) + lane] = er[(j << 6) + lane];
  }
  __syncthreads();
  // write out: float4 along hw (16B/lane), 256B segments per c
  const int hwq = t & 15, cg = t >> 4;
  const size_t base = ((size_t)b << 18);       // b*256*1024
  for (int it = 0; it < 16; ++it) {
    const int c = (it << 4) + cg;
    float4 v;
    v.x = sel[(hwq * 4 + 0) * 257 + c];
    v.y = sel[(hwq * 4 + 1) * 257 + c];
    v.z = sel[(hwq * 4 + 2) * 257 + c];
    v.w = sel[(hwq * 4 + 3) * 257 + c];
    *(float4*)(out + base + ((size_t)c << 10) + hw0 + (hwq << 2)) = v;
  }
}

extern "C" void kernel_launch(void* const* d_in, const int* in_sizes, int n_in,
                              void* d_out, int out_size, void* d_ws, size_t ws_size,
                              hipStream_t stream) {
  const float* x   = (const float*)d_in[0];
  const float* emb = (const float*)d_in[1];
  float* out  = (float*)d_out;
  float* loss = out + 8388608;

  char* ws = (char*)d_ws;
  unsigned short* eb = (unsigned short*)(ws);              // 524,288 B
  float* hn = (float*)(ws + 524288);                       //   4,096 B

  k_prep<<<64, 256, 0, stream>>>(emb, eb, hn, loss);
  k_fullk<<<512, 256, 0, stream>>>(x, eb, hn, emb, out, loss);
}

// Round 12
// 122.315 us; speedup vs baseline: 1.1533x; 1.1533x over previous
//
#include <hip/hip_runtime.h>

typedef short bf16x8 __attribute__((ext_vector_type(8)));
typedef float floatx4 __attribute__((ext_vector_type(4)));

// fp32 -> bf16 round-to-nearest-even (finite inputs)
static __device__ __forceinline__ unsigned short f2bf(float f) {
  unsigned int x = __float_as_uint(f);
  x += 0x7fffu + ((x >> 16) & 1u);
  return (unsigned short)(x >> 16);
}

// KT: blocks 0..511  : contiguous-geometry transpose x -> xbt[b][c/32][hw][32c] bf16
//                      + xn2 fp32 partials per c-group.  block = (b, g, hw-half):
//                      reads 64KB CONTIGUOUS x (1KB/wave-instr along hw, page-sequential),
//                      writes 4KB-contiguous xbt runs.  R11 post-mortem: every fused reader
//                      of x used 256B granules at 4KB stride -> DRAM page-activation-bound
//                      ~1.3TB/s when cold (the poison fill sweeps L3 every iteration); this
//                      kernel is the only x toucher and runs at streaming BW. xbt is written
//                      AFTER the fill -> k_fullk reads it warm.
//     blocks 512..575: emb -> eb bf16 + hn[k] = 0.5*||e_k||^2 ; block 512 zeroes loss.
__global__ __launch_bounds__(256) void k_trans(const float* __restrict__ x,
                                               const float* __restrict__ emb,
                                               unsigned short* __restrict__ xbt,
                                               float* __restrict__ xn2p,
                                               unsigned short* __restrict__ eb,
                                               float* __restrict__ hn,
                                               float* __restrict__ loss) {
  __shared__ float tile[32][260];              // 33,280 B; +4 pad decorrelates banks
  const int t = threadIdx.x, bid = blockIdx.x;
  if (bid < 512) {
    const int b = bid >> 4, g = (bid >> 1) & 7, h2 = bid & 1;
    const int hwbase = h2 << 9;                // this block: hw in [hwbase, hwbase+512)
    const float* xg = x + (((size_t)(b << 8) + (g << 5)) << 10);     // [b][g*32 + c][hw]
    unsigned short* xo = xbt + (((size_t)(b << 3) + g) << 15);       // + hw*32 + cc
    for (int ch = 0; ch < 2; ++ch) {
      const int hwc = hwbase + (ch << 8);      // 256-hw chunk
      // read: wave w covers c = w + i*4; lane l -> float4 #l of the row chunk (1KB/instr)
      {
        const int lane = t & 63, w = t >> 6;
        float4 vv[8];
#pragma unroll
        for (int i = 0; i < 8; ++i)
          vv[i] = *(const float4*)(xg + (((size_t)(w + (i << 2))) << 10) + hwc + (lane << 2));
#pragma unroll
        for (int i = 0; i < 8; ++i)
          *(float4*)(&tile[w + (i << 2)][lane << 2]) = vv[i];
      }
      __syncthreads();                         // tile complete
      // write: thread t = hw; column read tile[cc][t] (consecutive dwords: conflict-free);
      // fp32 ss (cc ascending); pack 4x bf16x8; 64B/thread -> 4KB/wave contiguous global
      {
        float ss = 0.f;
        bf16x8 o0, o1, o2, o3;
#pragma unroll
        for (int j = 0; j < 8; ++j) { const float v = tile[j][t];      ss += v * v; o0[j] = (short)f2bf(v); }
#pragma unroll
        for (int j = 0; j < 8; ++j) { const float v = tile[8 + j][t];  ss += v * v; o1[j] = (short)f2bf(v); }
#pragma unroll
        for (int j = 0; j < 8; ++j) { const float v = tile[16 + j][t]; ss += v * v; o2[j] = (short)f2bf(v); }
#pragma unroll
        for (int j = 0; j < 8; ++j) { const float v = tile[24 + j][t]; ss += v * v; o3[j] = (short)f2bf(v); }
        unsigned short* wp = xo + (((size_t)(hwc + t)) << 5);
        *(bf16x8*)(wp +  0) = o0;
        *(bf16x8*)(wp +  8) = o1;
        *(bf16x8*)(wp + 16) = o2;
        *(bf16x8*)(wp + 24) = o3;
        xn2p[(g << 15) + (b << 10) + hwc + t] = ss;
      }
      __syncthreads();                         // tile consumed before next chunk overwrites
    }
  } else {
    if (bid == 512 && t == 0) *loss = 0.f;     // k_fullk (later dispatch) is the only adder
    const int w = t >> 6, lane = t & 63;
    const int kb = ((bid - 512) << 4) + (w << 2);
    for (int jj = 0; jj < 4; ++jj) {
      const int k = kb + jj;
      const float* er = emb + (k << 8);
      unsigned short* eo = eb + (k << 8);
      float ss = 0.f;
      for (int j = 0; j < 4; ++j) {
        const float v = er[j * 64 + lane];
        ss += v * v;
        eo[j * 64 + lane] = f2bf(v);
      }
      for (int off = 32; off >= 1; off >>= 1) ss += __shfl_xor(ss, off, 64);
      if (lane == 0) hn[k] = 0.5f * ss;
    }
  }
}

// KB12: 512 blocks x 256 thr x 64 rows, FULL 1024 codes/block; A from xbt (warm, coalesced:
// per (rg,ci) wave-load = 1KB contiguous), E via the PROVEN R8 wave-private LDS-staged
// double-buffer (R11's reg-direct E spilled: VGPR capped 128, +32MB scratch, dur 141).
// Main body is barrier-free (staging + hn_l are wave-private); barriers only in the tail.
// bf16 values, MFMA order, compares bit-identical to R8 -> indices unchanged.
__global__ __launch_bounds__(256, 2) void k_fullk(const unsigned short* __restrict__ xbt,
                                                  const unsigned short* __restrict__ eb,
                                                  const float* __restrict__ hn,
                                                  const float* __restrict__ xn2p,
                                                  const float* __restrict__ emb,
                                                  float* __restrict__ out,
                                                  float* __restrict__ loss) {
  // LDS map (bytes):
  //   [0, 33792)        es0 (E dbuf 0); sel[64][257] f32 overlays [0,65792) at tail
  //   [33792, 67584)    es1 (E dbuf 1)
  //   [67584, 71680)    hn_l[1024] f32
  //   [71680, 72704)    bvs[4][64] f32
  //   [72704, 73728)    bis[4][64] i32
  //   [73728, 73984)    idx_l[64] i32
  //   [73984, 74240)    xn2_l[64] f32
  __shared__ __align__(16) char smem[74240];
  unsigned short* es0 = (unsigned short*)smem;
  unsigned short* es1 = (unsigned short*)(smem + 33792);
  float* sel   = (float*)smem;
  float* hn_l  = (float*)(smem + 67584);
  float* bvs   = (float*)(smem + 71680);
  int*   bis   = (int*)(smem + 72704);
  int*   idx_l = (int*)(smem + 73728);
  float* xn2_l = (float*)(smem + 73984);

  const int t = threadIdx.x;
  const int cq = t >> 6, lane = t & 63;        // wave = code-quarter
  const int r16 = lane & 15, quad = lane >> 4;
  const int n0 = blockIdx.x << 6;              // 64 rows/block
  const int b = n0 >> 10, hw0 = n0 & 1023;

  // A fragments from xbt: c = quad*8 + ci*32 + j -> group ci, cc = quad*8+j.
  // Per (rg,ci) wave-load: lane addr = r16*64B + quad*16B -> 1KB fully coalesced.
  bf16x8 a[4][8];
  for (int rg = 0; rg < 4; ++rg) {
    const int hw = hw0 + (rg << 4) + r16;
#pragma unroll
    for (int ci = 0; ci < 8; ++ci)
      a[rg][ci] = *(const bf16x8*)(xbt + (((size_t)(b << 3) + ci) << 15) + ((size_t)hw << 5) + (quad << 3));
  }
  // xn2: sum the 8 c-group partials (g ascending; deterministic)
  if (t < 64) {
    float s = 0.f;
#pragma unroll
    for (int g = 0; g < 8; ++g) s += xn2p[(g << 15) + n0 + t];
    xn2_l[t] = s;
  }
  // hn quarter fill: wave cq writes AND reads only its own quarter -> no barrier needed
  for (int i = 0; i < 4; ++i)
    hn_l[(cq << 8) + (i << 6) + lane] = hn[(cq << 8) + (i << 6) + lane];

  // staging (wave-private): thread (gg = t>>5, c32 = (t&31)*8 shorts) stages es rows gg*8+i.
  // wave w covers gg = 2w, 2w+1 -> rows 16w..16w+15 == exactly the rows wave cq=w reads.
  // es row r <-> code (r>>4)*256 + kt*16 + (r&15)
  const int gg = t >> 5, c32 = (t & 31) << 3;
  bf16x8 pf[8];
  {
#pragma unroll
    for (int i = 0; i < 8; ++i) {
      const int r = (gg << 3) + i;
      const int code = ((r >> 4) << 8) + (r & 15);                  // kt=0
      pf[i] = *(const bf16x8*)(eb + ((size_t)code << 8) + c32);
    }
#pragma unroll
    for (int i = 0; i < 8; ++i) *(bf16x8*)(&es0[((gg << 3) + i) * 264 + c32]) = pf[i];
#pragma unroll
    for (int i = 0; i < 8; ++i) {
      const int r = (gg << 3) + i;
      const int code = ((r >> 4) << 8) + 16 + (r & 15);             // kt=1
      pf[i] = *(const bf16x8*)(eb + ((size_t)code << 8) + c32);
    }
  }

  float bv[4][4]; int bi[4][4];
  for (int rg = 0; rg < 4; ++rg)
    for (int r = 0; r < 4; ++r) { bv[rg][r] = -3.4e38f; bi[rg][r] = 0; }

  // ---- main loop: barrier-free, wave-private es double-buffer (R8 form, proven) ----
  int cur = 0;
  for (int kt = 0; kt < 16; ++kt) {
    unsigned short* esc = cur ? es1 : es0;
    unsigned short* esn = cur ? es0 : es1;
    if (kt < 15)                               // write tile kt+1 (pf) into the other buffer
#pragma unroll
      for (int i = 0; i < 8; ++i) *(bf16x8*)(&esn[((gg << 3) + i) * 264 + c32]) = pf[i];
    if (kt < 14) {                             // issue prefetch of tile kt+2
#pragma unroll
      for (int i = 0; i < 8; ++i) {
        const int r = (gg << 3) + i;
        const int code = ((r >> 4) << 8) + ((kt + 2) << 4) + (r & 15);
        pf[i] = *(const bf16x8*)(eb + ((size_t)code << 8) + c32);
      }
    }
    // compute: this wave's 16 codes (es rows cq*16 + r16) vs the block's 64 rows
    const unsigned short* esr = &esc[((cq << 4) + r16) * 264 + (quad << 3)];
    floatx4 acc0 = {0.f,0.f,0.f,0.f}, acc1 = {0.f,0.f,0.f,0.f};
    floatx4 acc2 = {0.f,0.f,0.f,0.f}, acc3 = {0.f,0.f,0.f,0.f};
#pragma unroll
    for (int ci = 0; ci < 8; ++ci) {
      const bf16x8 bfr = *(const bf16x8*)(esr + (ci << 5));  // 1 read feeds 4 MFMAs
      acc0 = __builtin_amdgcn_mfma_f32_16x16x32_bf16(a[0][ci], bfr, acc0, 0, 0, 0);
      acc1 = __builtin_amdgcn_mfma_f32_16x16x32_bf16(a[1][ci], bfr, acc1, 0, 0, 0);
      acc2 = __builtin_amdgcn_mfma_f32_16x16x32_bf16(a[2][ci], bfr, acc2, 0, 0, 0);
      acc3 = __builtin_amdgcn_mfma_f32_16x16x32_bf16(a[3][ci], bfr, acc3, 0, 0, 0);
    }
    const int kglob = (cq << 8) + (kt << 4) + r16;
    const float h = hn_l[kglob];
#pragma unroll
    for (int r = 0; r < 4; ++r) {              // D: row = quad*4 + r, col(code) = r16
      float v;
      v = acc0[r] - h; if (v > bv[0][r]) { bv[0][r] = v; bi[0][r] = kglob; }
      v = acc1[r] - h; if (v > bv[1][r]) { bv[1][r] = v; bi[1][r] = kglob; }
      v = acc2[r] - h; if (v > bv[2][r]) { bv[2][r] = v; bi[2][r] = kglob; }
      v = acc3[r] - h; if (v > bv[3][r]) { bv[3][r] = v; bi[3][r] = kglob; }
    }
    cur ^= 1;                                  // wave-private flip; no barrier
  }

  // reduce across the 16 code-columns (within each 16-lane group); ties -> lowest index
  for (int off = 8; off >= 1; off >>= 1)
    for (int rg = 0; rg < 4; ++rg)
      for (int r = 0; r < 4; ++r) {
        const float ov = __shfl_xor(bv[rg][r], off, 64);
        const int   oi = __shfl_xor(bi[rg][r], off, 64);
        if (ov > bv[rg][r] || (ov == bv[rg][r] && oi < bi[rg][r])) { bv[rg][r] = ov; bi[rg][r] = oi; }
      }
  if (r16 == 0) {
    for (int rg = 0; rg < 4; ++rg)
      for (int r = 0; r < 4; ++r) {
        const int row = (rg << 4) + (quad << 2) + r;
        bvs[(cq << 6) + row] = bv[rg][r];
        bis[(cq << 6) + row] = bi[rg][r];
      }
  }
  __syncthreads();                             // all quarters' bvs/bis visible

  // merge the 4 code-quarters (ascending q: strict > keeps lowest code on ties) + loss
  if (t < 64) {
    float vm = bvs[t]; int im = bis[t];
    for (int q = 1; q < 4; ++q) {
      const float v = bvs[(q << 6) + t];
      if (v > vm) { vm = v; im = bis[(q << 6) + t]; }
    }
    idx_l[t] = im;
    float lv = xn2_l[t] - 2.f * vm;            // = ||x_n - e_{im}||^2
    for (int off = 32; off >= 1; off >>= 1) lv += __shfl_xor(lv, off, 64);
    if (t == 0) atomicAdd(loss, lv * (1.25f / 8388608.0f));
  }
  __syncthreads();                             // es dead + idx_l ready; sel may overwrite

  // gather winning code rows into LDS (coalesced 256B loads from L2-resident emb)
  for (int i = 0; i < 16; ++i) {
    const int row = (cq << 4) + i;
    const float* er = emb + ((size_t)idx_l[row] << 8);
    for (int j = 0; j < 4; ++j)
      sel[row * 257 + (j << 6) + lane] = er[(j << 6) + lane];
  }
  __syncthreads();
  // write out: float4 along hw (16B/lane), 256B segments per c
  const int hwq = t & 15, cg = t >> 4;
  const size_t base = ((size_t)b << 18);       // b*256*1024
  for (int it = 0; it < 16; ++it) {
    const int c = (it << 4) + cg;
    float4 v;
    v.x = sel[(hwq * 4 + 0) * 257 + c];
    v.y = sel[(hwq * 4 + 1) * 257 + c];
    v.z = sel[(hwq * 4 + 2) * 257 + c];
    v.w = sel[(hwq * 4 + 3) * 257 + c];
    *(float4*)(out + base + ((size_t)c << 10) + hw0 + (hwq << 2)) = v;
  }
}

extern "C" void kernel_launch(void* const* d_in, const int* in_sizes, int n_in,
                              void* d_out, int out_size, void* d_ws, size_t ws_size,
                              hipStream_t stream) {
  const float* x   = (const float*)d_in[0];
  const float* emb = (const float*)d_in[1];
  float* out  = (float*)d_out;
  float* loss = out + 8388608;

  char* ws = (char*)d_ws;
  unsigned short* xbt = (unsigned short*)(ws);             // 16,777,216 B
  unsigned short* eb  = (unsigned short*)(ws + 16777216);  //    524,288 B
  float* hn   = (float*)(ws + 17301504);                   //      4,096 B
  float* xn2p = (float*)(ws + 17305600);                   //  1,048,576 B

  k_trans<<<576, 256, 0, stream>>>(x, emb, xbt, xn2p, eb, hn, loss);
  k_fullk<<<512, 256, 0, stream>>>(xbt, eb, hn, xn2p, emb, out, loss);
}

// Round 13
// 112.418 us; speedup vs baseline: 1.2548x; 1.0880x over previous
//
#include <hip/hip_runtime.h>

typedef short bf16x8 __attribute__((ext_vector_type(8)));
typedef short bf16x4 __attribute__((ext_vector_type(4)));
typedef float floatx4 __attribute__((ext_vector_type(4)));

// fp32 -> bf16 round-to-nearest-even (finite inputs)
static __device__ __forceinline__ unsigned short f2bf(float f) {
  unsigned int x = __float_as_uint(f);
  x += 0x7fffu + ((x >> 16) & 1u);
  return (unsigned short)(x >> 16);
}

// KP (emb only, 64 blocks): emb -> eb bf16 + hn[k] = 0.5*||e_k||^2 ; block 0 zeroes loss.
__global__ __launch_bounds__(256) void k_prep(const float* __restrict__ emb,
                                              unsigned short* __restrict__ eb,
                                              float* __restrict__ hn,
                                              float* __restrict__ loss) {
  const int t = threadIdx.x, bid = blockIdx.x;
  if (bid == 0 && t == 0) *loss = 0.f;       // k_fullk (later dispatch) is the only reader/adder
  const int w = t >> 6, lane = t & 63;
  const int kb = (bid << 4) + (w << 2);
  for (int jj = 0; jj < 4; ++jj) {
    const int k = kb + jj;
    const float* er = emb + (k << 8);
    unsigned short* eo = eb + (k << 8);
    float ss = 0.f;
    for (int j = 0; j < 4; ++j) {
      const float v = er[j * 64 + lane];
      ss += v * v;
      eo[j * 64 + lane] = f2bf(v);
    }
    for (int off = 32; off >= 1; off >>= 1) ss += __shfl_xor(ss, off, 64);
    if (lane == 0) hn[k] = 0.5f * ss;
  }
}

// KB13 == KB7/R8 REVERT (session best, 112.2us). 512 blocks x 256 thr x 64 rows, full 1024
// codes/block, fused ingest+argmax+output.
// Why this exact structure won the session (12-round record):
//  - fused phase-0 (float4 x ingest + two-stage LDS transpose): splitting it out with a
//    contiguous transpose (R12) cost +10us net (xbt round-trip > cold-page savings).
//  - E via wave-private LDS double-buffer, BARRIER-FREE main loop: per-tile __syncthreads
//    cost +30us (R2/R4); E direct-to-register spilled past the 128-VGPR cap, +29us (R11).
//  - MLP batching of the x loads and s_setprio: neutral (R9).
// Residual profile: ~66us timed, NO busy pipe (Mfma 9%, VALU 12%, HBM 11-16%) -- a
// latency floor at 2 waves/SIMD that survived every structural alternative tried.
__global__ __launch_bounds__(256, 2) void k_fullk(const float* __restrict__ x,
                                                  const unsigned short* __restrict__ eb,
                                                  const float* __restrict__ hn,
                                                  const float* __restrict__ emb,
                                                  float* __restrict__ out,
                                                  float* __restrict__ loss) {
  // LDS map (bytes):
  //   [0, 33792)        tile2[64*264] shorts == es0 (E dbuf 0); sel f32 overlays at tail
  //   [33792, 67584)    tmp[256*64] shorts (32768 B) == es1 (E dbuf 1)
  //   [67584, 71680)    xred2[4][256] f32 (prologue) == hn_l[1024] f32 (main loop)
  //   [71680, 72704)    bvs[4][64] f32
  //   [72704, 73728)    bis[4][64] i32
  //   [73728, 73984)    idx_l[64] i32
  //   [73984, 74240)    xn2_l[64] f32
  __shared__ __align__(16) char smem[74240];
  unsigned short* es0 = (unsigned short*)smem;
  unsigned short* es1 = (unsigned short*)(smem + 33792);
  unsigned short* tile2 = es0;
  unsigned short* tmp   = es1;
  float* sel   = (float*)smem;
  float* hn_l  = (float*)(smem + 67584);
  float* xred2 = (float*)(smem + 67584);
  float* bvs   = (float*)(smem + 71680);
  int*   bis   = (int*)(smem + 72704);
  int*   idx_l = (int*)(smem + 73728);
  float* xn2_l = (float*)(smem + 73984);

  const int t = threadIdx.x;
  const int cq = t >> 6, lane = t & 63;        // wave = code-quarter
  const int r16 = lane & 15, quad = lane >> 4;
  const int n0 = blockIdx.x << 6;              // 64 rows/block
  const int b = n0 >> 10, hw0 = n0 & 1023;

  // staging geometry (wave-private: wave w stages es rows 16w..16w+15 == rows wave cq=w reads)
  const int g = t >> 5, c32 = (t & 31) << 3;

  // ---- step 1: issue E-tile0 loads EARLY (latency hides under the x read) ----
  bf16x8 pf0[8];
#pragma unroll
  for (int i = 0; i < 8; ++i) {
    const int r = (g << 3) + i;
    const int code = ((r >> 4) << 8) + (r & 15);                    // kt=0
    pf0[i] = *(const bf16x8*)(eb + ((size_t)code << 8) + c32);
  }

  // ---- stage A: x float4 loads -> tmp[c][hw] (bf16), per-thread row-split ss ----
  {
    const int hwq = t & 15, cidx = t >> 4;
    const float* xpb = x + ((size_t)b << 18) + hw0 + (hwq << 2);
    float ss0 = 0.f, ss1 = 0.f, ss2 = 0.f, ss3 = 0.f;
    for (int p = 0; p < 16; ++p) {
      const int c = (p << 4) + cidx;
      const float4 v = *(const float4*)(xpb + ((size_t)c << 10));
      ss0 += v.x * v.x; ss1 += v.y * v.y; ss2 += v.z * v.z; ss3 += v.w * v.w;
      bf16x4 u;
      u[0] = (short)f2bf(v.x); u[1] = (short)f2bf(v.y);
      u[2] = (short)f2bf(v.z); u[3] = (short)f2bf(v.w);
      *(bf16x4*)(&tmp[(c << 6) + (hwq << 2)]) = u;                  // tmp[c*64 + hw]
    }
    xred2[t] = ss0; xred2[256 + t] = ss1; xred2[512 + t] = ss2; xred2[768 + t] = ss3;
  }
  __syncthreads();                             // tmp + xred2 complete

  // ---- stage B: tmp[c][hw] -> tile2[hw][c] (b16 reads 2-lanes/dword: conflict-free) ----
  {
    const int row = t & 63, wv = t >> 6;
    for (int s = 0; s < 8; ++s) {
      const int c8 = wv + (s << 2);
      bf16x8 u;
#pragma unroll
      for (int k = 0; k < 8; ++k) u[k] = (short)tmp[(((c8 << 3) + k) << 6) + row];
      *(bf16x8*)(&tile2[row * 264 + (c8 << 3)]) = u;
    }
  }
  // xn2 reduce (wave 0; hn_l overlay of xred2 happens after the barrier below)
  if (t < 64) {
    float s = 0.f;
    for (int ci2 = 0; ci2 < 16; ++ci2)
      s += xred2[(t & 3) * 256 + (ci2 << 4) + (t >> 2)];
    xn2_l[t] = s;
  }
  __syncthreads();                             // tile2 complete; xred2 consumed

  // A fragments from tile2: rows rg*16 + r16, c = quad*8 + ci*32
  bf16x8 a[4][8];
  for (int rg = 0; rg < 4; ++rg) {
    const unsigned short* tr = tile2 + ((rg << 4) + r16) * 264 + (quad << 3);
#pragma unroll
    for (int ci = 0; ci < 8; ++ci) a[rg][ci] = *(const bf16x8*)(tr + (ci << 5));
  }
  // hn quarter, WAVE-PRIVATE (overlays xred2 -- dead now)
  for (int i = 0; i < 4; ++i)
    hn_l[(cq << 8) + (i << 6) + lane] = hn[(cq << 8) + (i << 6) + lane];
  __syncthreads();                             // tile2 consumed by all; es0 free

  // ---- E prologue: write preloaded tile0 -> es0; issue tile1 prefetch ----
  bf16x8 pf[8];
#pragma unroll
  for (int i = 0; i < 8; ++i) *(bf16x8*)(&es0[((g << 3) + i) * 264 + c32]) = pf0[i];
#pragma unroll
  for (int i = 0; i < 8; ++i) {
    const int r = (g << 3) + i;
    const int code = ((r >> 4) << 8) + 16 + (r & 15);               // kt=1
    pf[i] = *(const bf16x8*)(eb + ((size_t)code << 8) + c32);
  }

  float bv[4][4]; int bi[4][4];
  for (int rg = 0; rg < 4; ++rg)
    for (int r = 0; r < 4; ++r) { bv[rg][r] = -3.4e38f; bi[rg][r] = 0; }

  // ---- main loop: barrier-free, wave-private es double-buffer ----
  int cur = 0;
  for (int kt = 0; kt < 16; ++kt) {
    unsigned short* esc = cur ? es1 : es0;
    unsigned short* esn = cur ? es0 : es1;
    if (kt < 15)                               // write tile kt+1 (pf) into the other buffer
#pragma unroll
      for (int i = 0; i < 8; ++i) *(bf16x8*)(&esn[((g << 3) + i) * 264 + c32]) = pf[i];
    if (kt < 14) {                             // issue prefetch of tile kt+2
#pragma unroll
      for (int i = 0; i < 8; ++i) {
        const int r = (g << 3) + i;
        const int code = ((r >> 4) << 8) + ((kt + 2) << 4) + (r & 15);
        pf[i] = *(const bf16x8*)(eb + ((size_t)code << 8) + c32);
      }
    }
    // compute: this wave's 16 codes (es rows cq*16 + r16) vs the block's 64 rows
    const unsigned short* esr = &esc[((cq << 4) + r16) * 264 + (quad << 3)];
    floatx4 acc0 = {0.f,0.f,0.f,0.f}, acc1 = {0.f,0.f,0.f,0.f};
    floatx4 acc2 = {0.f,0.f,0.f,0.f}, acc3 = {0.f,0.f,0.f,0.f};
#pragma unroll
    for (int ci = 0; ci < 8; ++ci) {
      const bf16x8 bfr = *(const bf16x8*)(esr + (ci << 5));  // 1 read feeds 4 MFMAs
      acc0 = __builtin_amdgcn_mfma_f32_16x16x32_bf16(a[0][ci], bfr, acc0, 0, 0, 0);
      acc1 = __builtin_amdgcn_mfma_f32_16x16x32_bf16(a[1][ci], bfr, acc1, 0, 0, 0);
      acc2 = __builtin_amdgcn_mfma_f32_16x16x32_bf16(a[2][ci], bfr, acc2, 0, 0, 0);
      acc3 = __builtin_amdgcn_mfma_f32_16x16x32_bf16(a[3][ci], bfr, acc3, 0, 0, 0);
    }
    const int kglob = (cq << 8) + (kt << 4) + r16;
    const float h = hn_l[kglob];
#pragma unroll
    for (int r = 0; r < 4; ++r) {              // D: row = quad*4 + r, col(code) = r16
      float v;
      v = acc0[r] - h; if (v > bv[0][r]) { bv[0][r] = v; bi[0][r] = kglob; }
      v = acc1[r] - h; if (v > bv[1][r]) { bv[1][r] = v; bi[1][r] = kglob; }
      v = acc2[r] - h; if (v > bv[2][r]) { bv[2][r] = v; bi[2][r] = kglob; }
      v = acc3[r] - h; if (v > bv[3][r]) { bv[3][r] = v; bi[3][r] = kglob; }
    }
    cur ^= 1;                                  // wave-private flip; no barrier
  }

  // reduce across the 16 code-columns (within each 16-lane group); ties -> lowest index
  for (int off = 8; off >= 1; off >>= 1)
    for (int rg = 0; rg < 4; ++rg)
      for (int r = 0; r < 4; ++r) {
        const float ov = __shfl_xor(bv[rg][r], off, 64);
        const int   oi = __shfl_xor(bi[rg][r], off, 64);
        if (ov > bv[rg][r] || (ov == bv[rg][r] && oi < bi[rg][r])) { bv[rg][r] = ov; bi[rg][r] = oi; }
      }
  if (r16 == 0) {
    for (int rg = 0; rg < 4; ++rg)
      for (int r = 0; r < 4; ++r) {
        const int row = (rg << 4) + (quad << 2) + r;
        bvs[(cq << 6) + row] = bv[rg][r];
        bis[(cq << 6) + row] = bi[rg][r];
      }
  }
  __syncthreads();                             // all quarters' bvs/bis visible

  // merge the 4 code-quarters (ascending q: strict > keeps lowest code on ties) + loss
  if (t < 64) {
    float vm = bvs[t]; int im = bis[t];
    for (int q = 1; q < 4; ++q) {
      const float v = bvs[(q << 6) + t];
      if (v > vm) { vm = v; im = bis[(q << 6) + t]; }
    }
    idx_l[t] = im;
    float lv = xn2_l[t] - 2.f * vm;            // = ||x_n - e_{im}||^2
    for (int off = 32; off >= 1; off >>= 1) lv += __shfl_xor(lv, off, 64);
    if (t == 0) atomicAdd(loss, lv * (1.25f / 8388608.0f));
  }
  __syncthreads();                             // es dead + idx_l ready; sel may overwrite

  // gather winning code rows into LDS (coalesced 256B loads from L2-resident emb)
  for (int i = 0; i < 16; ++i) {
    const int row = (cq << 4) + i;
    const float* er = emb + ((size_t)idx_l[row] << 8);
    for (int j = 0; j < 4; ++j)
      sel[row * 257 + (j << 6) + lane] = er[(j << 6) + lane];
  }
  __syncthreads();
  // write out: float4 along hw (16B/lane), 256B segments per c
  const int hwq = t & 15, cg = t >> 4;
  const size_t base = ((size_t)b << 18);       // b*256*1024
  for (int it = 0; it < 16; ++it) {
    const int c = (it << 4) + cg;
    float4 v;
    v.x = sel[(hwq * 4 + 0) * 257 + c];
    v.y = sel[(hwq * 4 + 1) * 257 + c];
    v.z = sel[(hwq * 4 + 2) * 257 + c];
    v.w = sel[(hwq * 4 + 3) * 257 + c];
    *(float4*)(out + base + ((size_t)c << 10) + hw0 + (hwq << 2)) = v;
  }
}

extern "C" void kernel_launch(void* const* d_in, const int* in_sizes, int n_in,
                              void* d_out, int out_size, void* d_ws, size_t ws_size,
                              hipStream_t stream) {
  const float* x   = (const float*)d_in[0];
  const float* emb = (const float*)d_in[1];
  float* out  = (float*)d_out;
  float* loss = out + 8388608;

  char* ws = (char*)d_ws;
  unsigned short* eb = (unsigned short*)(ws);              // 524,288 B
  float* hn = (float*)(ws + 524288);                       //   4,096 B

  k_prep<<<64, 256, 0, stream>>>(emb, eb, hn, loss);
  k_fullk<<<512, 256, 0, stream>>>(x, eb, hn, emb, out, loss);
}